// Round 10
// baseline (16789.220 us; speedup 1.0000x reference)
//
#include <hip/hip_runtime.h>

// CustomGRU: B=256, T=1024, I=128, H=256.  out = concat(output[B,T,H], h_last[B,H]) f32.
//
// R10: MFMA recurrence via error-free bf16x3 decomposition (6-term composite K=1536;
// dropped terms ~2^-27 => f32-class accuracy). 8 groups (same-XCD, bid&7) x 32 WGs;
// WG owns 8 units x 32 batches. Per step: gather 32KB h (f32, L2) -> split to 3 bf16
// parts in LDS (XOR-swizzled) -> 96x mfma_f32_32x32x16_bf16 K-split over 8 waves
// (B-frags: 48 VGPR/wave, loaded once, asm-pinned = R9-proven-resident size) ->
// partial combine in LDS -> gates -> publish + per-WG release flag (parity
// double-buffered; bounded spins so bugs surface as wrong answers, not hangs).

#define B_SZ 256
#define T_SZ 1024
#define H_SZ 256
#define G3   768
#define SPIN_MAX (1 << 27)

typedef __attribute__((ext_vector_type(8)))  short short8b;
typedef __attribute__((ext_vector_type(16))) float f32x16;

// ws layout (bytes)
#define XCHH_OFF  0ull          // float xch[8][2][256 unit][32 batch] = 2,097,152
#define FLAG_OFF  2097152ull    // unsigned flags[8][2][32]            = 2,048 (pad 4K)
#define WSP_OFF   2101248ull    // ushort wsplit[3][768][256]          = 1,179,648
#define GX_OFF    3280896ull    // f32 gx chunk: TC * 786,432 B

// round-to-nearest-even f32 -> bf16 bits
__device__ __forceinline__ unsigned short bf16_rne(float f) {
    unsigned u = __float_as_uint(f);
    unsigned r = (u + 0x7FFFu + ((u >> 16) & 1u)) >> 16;
    return (unsigned short)r;
}
__device__ __forceinline__ float bf16_f32(unsigned short s) {
    return __uint_as_float(((unsigned)s) << 16);
}
__device__ __forceinline__ void split3(float h, unsigned short& s0,
                                       unsigned short& s1, unsigned short& s2) {
    s0 = bf16_rne(h);
    float r1 = h - bf16_f32(s0);
    s1 = bf16_rne(r1);
    float r2 = r1 - bf16_f32(s1);
    s2 = bf16_rne(r2);
}

// ---------------- prep: W bf16x3 split, h0 exchange init, flags=0 ----------------
__global__ void prep_kernel(const float* __restrict__ h0,
                            const float* __restrict__ whh,
                            float* __restrict__ xch,
                            unsigned* __restrict__ flags,
                            unsigned short* __restrict__ wsp) {
    int tid = blockIdx.x * blockDim.x + threadIdx.x;   // grid covers 196608
    if (tid < G3 * H_SZ) {
        unsigned short s0, s1, s2;
        split3(whh[tid], s0, s1, s2);
        wsp[tid] = s0;
        wsp[G3 * H_SZ + tid] = s1;
        wsp[2 * G3 * H_SZ + tid] = s2;
    }
    if (tid < B_SZ * H_SZ) {
        int b = tid >> 8, u = tid & 255;
        int g = b >> 5, m = b & 31;
        float v = h0[tid];
        xch[((size_t)(g * 2 + 0) * 256 + u) * 32 + m] = v;
        xch[((size_t)(g * 2 + 1) * 256 + u) * 32 + m] = v;
    }
    if (tid < 512) flags[tid] = 0u;
}

// ---------------- phase 1: gx = x @ W_ih^T (R9 kernel, unchanged) ----------------
__global__ __launch_bounds__(256) void gemm_x_kernel(
    const float* __restrict__ x, const float* __restrict__ wih,
    float* __restrict__ gx, int c, int tcShift)
{
    __shared__ __align__(16) float xs[64][132];
    __shared__ __align__(16) float ws[128][68];
    const int TC = 1 << tcShift;
    const int t  = threadIdx.x;
    const int bx = blockIdx.x, by = blockIdx.y;

#pragma unroll
    for (int i = 0; i < 8; ++i) {
        int f4 = t + i * 256;
        int r  = f4 >> 5, c4 = (f4 & 31) * 4;
        int rho = bx * 64 + r;
        int b = rho >> tcShift, u = rho & (TC - 1);
        float4 v = *(const float4*)(x + ((size_t)b * T_SZ + (size_t)c * TC + u) * 128 + c4);
        *(float4*)&xs[r][c4] = v;
    }

    const int gl = t & 31;
    const int rl = t >> 5;
    float acc[8][4];
#pragma unroll
    for (int i = 0; i < 8; ++i)
#pragma unroll
        for (int jj = 0; jj < 4; ++jj) acc[i][jj] = 0.f;

    for (int kb = 0; kb < 2; ++kb) {
        __syncthreads();
#pragma unroll
        for (int i = 0; i < 8; ++i) {
            int f4 = t + i * 256;
            int row = f4 >> 4, c4 = (f4 & 15) * 4;
            float4 v = *(const float4*)(wih + (size_t)(by * 128 + row) * 128 + kb * 64 + c4);
            *(float4*)&ws[row][c4] = v;
        }
        __syncthreads();

#pragma unroll 4
        for (int k4 = 0; k4 < 16; ++k4) {
            float4 wv0 = *(const float4*)&ws[gl     ][k4 * 4];
            float4 wv1 = *(const float4*)&ws[gl + 32][k4 * 4];
            float4 wv2 = *(const float4*)&ws[gl + 64][k4 * 4];
            float4 wv3 = *(const float4*)&ws[gl + 96][k4 * 4];
#pragma unroll
            for (int rr = 0; rr < 8; ++rr) {
                float4 xv = *(const float4*)&xs[rl + rr * 8][kb * 64 + k4 * 4];
                acc[rr][0] = fmaf(xv.w, wv0.w, fmaf(xv.z, wv0.z, fmaf(xv.y, wv0.y, fmaf(xv.x, wv0.x, acc[rr][0]))));
                acc[rr][1] = fmaf(xv.w, wv1.w, fmaf(xv.z, wv1.z, fmaf(xv.y, wv1.y, fmaf(xv.x, wv1.x, acc[rr][1]))));
                acc[rr][2] = fmaf(xv.w, wv2.w, fmaf(xv.z, wv2.z, fmaf(xv.y, wv2.y, fmaf(xv.x, wv2.x, acc[rr][2]))));
                acc[rr][3] = fmaf(xv.w, wv3.w, fmaf(xv.z, wv3.z, fmaf(xv.y, wv3.y, fmaf(xv.x, wv3.x, acc[rr][3]))));
            }
        }
    }

#pragma unroll
    for (int rr = 0; rr < 8; ++rr) {
        size_t base = (size_t)(bx * 64 + rl + rr * 8) * G3 + by * 128 + gl;
#pragma unroll
        for (int gi = 0; gi < 4; ++gi)
            gx[base + 32 * gi] = acc[rr][gi];
    }
}

#define PINV(xv) { float4* _p = (float4*)&(xv); \
    asm volatile("" : "+v"(_p->x), "+v"(_p->y), "+v"(_p->z), "+v"(_p->w)); }

// ---------------- phase 2: MFMA recurrence ----------------
// bid: g = bid&7 (group, same XCD), w = bid>>3 (0..31), u0 = 8w.
// Composite positions (A-part, B-part): (0,0)(0,1)(1,0)(0,2)(2,0)(1,1).
// Wave kv = t>>6 owns klocal-tiles {2kv,2kv+1} x 6 positions = 12 MFMA; B-frags
// (12 x short8b = 48 VGPR) loaded once and pinned. A-parts in LDS, 16B-chunk
// XOR-swizzle (chunk ^ m) => conflict-free ds_read_b128 fragments.
__global__ __launch_bounds__(512) void gru_kernel(
    const float* __restrict__ gx, const unsigned short* __restrict__ wsp,
    const float* __restrict__ bih, const float* __restrict__ bhh,
    float* __restrict__ xch, unsigned* __restrict__ flags,
    float* __restrict__ out, int gbase, int tc, int isLast)
{
    __shared__ __align__(16) unsigned short APART[3 * 32 * 256]; // 49152 B
    __shared__ __align__(16) float CP[8 * 32 * 36];              // 36864 B
    __shared__ float HOLD[32][8];                                // 1024 B

    const int t   = threadIdx.x;
    const int bid = blockIdx.x;
    const int g   = bid & 7;
    const int w   = bid >> 3;
    const int u0  = w * 8;

    const int lane = t & 63;
    const int kv   = t >> 6;      // wave 0..7
    const int l5   = lane >> 5;
    const int col  = lane & 31;

    // ---- B fragments (register-resident, pinned) ----
    short8b bf[6][2];
    {
        const int pBt[6] = {0, 1, 0, 2, 0, 1};
        const int q = col >> 3, j = col & 7;
        const int rowv = q * 256 + u0 + j;          // valid iff col < 24
#pragma unroll
        for (int pos = 0; pos < 6; ++pos) {
#pragma unroll
            for (int tli = 0; tli < 2; ++tli) {
                const int ktl = 2 * kv + tli;
                const int kb  = ktl * 16 + l5 * 8;
                if (col < 24) {
                    bf[pos][tli] = *(const short8b*)(
                        wsp + ((size_t)pBt[pos] * G3 + rowv) * 256 + kb);
                } else {
                    short8b z = {0, 0, 0, 0, 0, 0, 0, 0};
                    bf[pos][tli] = z;
                }
            }
        }
    }
#pragma unroll
    for (int pos = 0; pos < 6; ++pos) { PINV(bf[pos][0]) PINV(bf[pos][1]) }

    // ---- epilogue-thread invariants ----
    const int m_e = t & 31, j_e = (t >> 5) & 7;
    const int b_e = 32 * g + m_e;
    float bsr = 0.f, bsz = 0.f, bsn = 0.f;
    if (t < 256) {
        int ju = u0 + j_e;
        bsr = bih[ju]       + bhh[ju];
        bsz = bih[256 + ju] + bhh[256 + ju];
        bsn = bih[512 + ju] + bhh[512 + ju];
    }

    float* xg = xch;            // [g][par][unit][batch]
    unsigned* fl = flags;       // [g][par][w]

#pragma unroll 1
    for (int u = 0; u < tc; ++u) {
        const int tg  = gbase + u;
        const int par = tg & 1;

        // ---- wait for all 32 WGs' h(tg) flags ----
        if (t < 32) {
            unsigned* fp = fl + (g * 2 + par) * 32 + t;
            unsigned v = __hip_atomic_load(fp, __ATOMIC_ACQUIRE, __HIP_MEMORY_SCOPE_AGENT);
            int sp = 0;
            while (v < (unsigned)tg && sp < SPIN_MAX) {
                __builtin_amdgcn_s_sleep(2);
                v = __hip_atomic_load(fp, __ATOMIC_ACQUIRE, __HIP_MEMORY_SCOPE_AGENT);
                ++sp;
            }
        }
        __syncthreads();

        // ---- gather h (L2, coalesced) + bf16x3 split -> APART (swizzled) ----
        {
            const int m = t & 31;
            const float* src = xg + ((size_t)(g * 2 + par) * 256) * 32;
#pragma unroll
            for (int h8 = 0; h8 < 2; ++h8) {
                const int oct = (t >> 5) + 16 * h8;   // 0..31
                float hv[8];
#pragma unroll
                for (int i = 0; i < 8; ++i)
                    hv[i] = __hip_atomic_load(src + (size_t)(oct * 8 + i) * 32 + m,
                                              __ATOMIC_RELAXED, __HIP_MEMORY_SCOPE_AGENT);
                short8b v0, v1, v2;
#pragma unroll
                for (int i = 0; i < 8; ++i) {
                    unsigned short s0, s1, s2;
                    split3(hv[i], s0, s1, s2);
                    v0[i] = (short)s0; v1[i] = (short)s1; v2[i] = (short)s2;
                }
                const int slot = oct ^ m;
                *(short8b*)(APART + (size_t)(0 * 32 + m) * 256 + slot * 8) = v0;
                *(short8b*)(APART + (size_t)(1 * 32 + m) * 256 + slot * 8) = v1;
                *(short8b*)(APART + (size_t)(2 * 32 + m) * 256 + slot * 8) = v2;
                if (oct == w) {
#pragma unroll
                    for (int i = 0; i < 8; ++i) HOLD[m][i] = hv[i];
                }
            }
        }
        // gx for this step (consumed in epilogue; latency hides under MFMA)
        float gxr = 0.f, gxz = 0.f, gxn = 0.f;
        if (t < 256) {
            const float* gp = gx + ((size_t)b_e * tc + u) * G3 + u0 + j_e;
            gxr = gp[0]; gxz = gp[256]; gxn = gp[512];
        }
        __syncthreads();

        // ---- MFMA phase: 12 per wave, K-split partials ----
        {
            const int pAt[6] = {0, 0, 1, 0, 2, 1};
            short8b ar[3][2];
            const int m = col;   // A-row = lane&31
#pragma unroll
            for (int part = 0; part < 3; ++part) {
#pragma unroll
                for (int tli = 0; tli < 2; ++tli) {
                    const int chunk = (2 * kv + tli) * 2 + l5;
                    const int slot  = chunk ^ m;
                    ar[part][tli] = *(const short8b*)(
                        APART + (size_t)(part * 32 + m) * 256 + slot * 8);
                }
            }
            f32x16 acc;
#pragma unroll
            for (int i = 0; i < 16; ++i) acc[i] = 0.f;
#pragma unroll
            for (int pos = 0; pos < 6; ++pos) {
#pragma unroll
                for (int tli = 0; tli < 2; ++tli) {
                    acc = __builtin_amdgcn_mfma_f32_32x32x16_bf16(
                        ar[pAt[pos]][tli], bf[pos][tli], acc, 0, 0, 0);
                }
            }
            // C/D (verified m74/m101): col = lane&31, row = (reg&3)+8*(reg>>2)+4*(lane>>5)
            float* cp = CP + (size_t)kv * (32 * 36) + (size_t)col * 36;
#pragma unroll
            for (int rg = 0; rg < 4; ++rg) {
                float4 v;
                v.x = acc[4 * rg]; v.y = acc[4 * rg + 1];
                v.z = acc[4 * rg + 2]; v.w = acc[4 * rg + 3];
                *(float4*)(cp + 8 * rg + 4 * l5) = v;
            }
        }
        __syncthreads();

        // ---- epilogue: combine partials, gates, publish ----
        if (t < 256) {
            float sr = 0.f, sz = 0.f, sn = 0.f;
#pragma unroll
            for (int w8 = 0; w8 < 8; ++w8) {
                const float* cp = CP + (size_t)w8 * (32 * 36);
                sr += cp[(0  + j_e) * 36 + m_e];
                sz += cp[(8  + j_e) * 36 + m_e];
                sn += cp[(16 + j_e) * 36 + m_e];
            }
            float ar_ = sr + gxr + bsr;
            float az_ = sz + gxz + bsz;
            float an_ = sn + gxn + bsn;
            float r  = 1.f / (1.f + expf(-ar_));
            float z  = 1.f / (1.f + expf(-az_));
            float nn = tanhf(r * an_);
            float hold = HOLD[m_e][j_e];
            float hn = (1.f - z) * hold + z * nn;

            __hip_atomic_store(
                xg + ((size_t)(g * 2 + ((tg + 1) & 1)) * 256 + (u0 + j_e)) * 32 + m_e,
                hn, __ATOMIC_RELAXED, __HIP_MEMORY_SCOPE_AGENT);
            out[((size_t)b_e * T_SZ + tg) * H_SZ + u0 + j_e] = hn;
            if (isLast && u == tc - 1)
                out[(size_t)B_SZ * T_SZ * H_SZ + (size_t)b_e * H_SZ + u0 + j_e] = hn;
        }
        __syncthreads();   // drains all publish stores (vmcnt 0) before the flag
        if (t == 0) {
            __hip_atomic_store(fl + (g * 2 + ((tg + 1) & 1)) * 32 + w,
                               (unsigned)(tg + 1),
                               __ATOMIC_RELEASE, __HIP_MEMORY_SCOPE_AGENT);
        }
    }
}

// ---------------- host ----------------
extern "C" void kernel_launch(void* const* d_in, const int* in_sizes, int n_in,
                              void* d_out, int out_size, void* d_ws, size_t ws_size,
                              hipStream_t stream) {
    const float* x   = (const float*)d_in[0];
    const float* h0  = (const float*)d_in[1];
    const float* wih = (const float*)d_in[2];
    const float* whh = (const float*)d_in[3];
    const float* bih = (const float*)d_in[4];
    const float* bhh = (const float*)d_in[5];
    float* out = (float*)d_out;

    char* ws = (char*)d_ws;
    float*          xch   = (float*)(ws + XCHH_OFF);
    unsigned*       flags = (unsigned*)(ws + FLAG_OFF);
    unsigned short* wsp   = (unsigned short*)(ws + WSP_OFF);
    float*          gxb   = (float*)(ws + GX_OFF);

    int tcShift = 10;
    while (tcShift > 0 && GX_OFF + (786432ull << tcShift) > ws_size) --tcShift;
    const int TC  = 1 << tcShift;
    const int nCh = T_SZ / TC;

    prep_kernel<<<dim3(768), dim3(256), 0, stream>>>(h0, whh, xch, flags, wsp);
    for (int c = 0; c < nCh; ++c) {
        gemm_x_kernel<<<dim3(B_SZ * TC / 64, 6), dim3(256), 0, stream>>>(
            x, wih, gxb, c, tcShift);
        gru_kernel<<<dim3(256), dim3(512), 0, stream>>>(
            gxb, wsp, bih, bhh, xch, flags, out, c * TC, TC, (c == nCh - 1) ? 1 : 0);
    }
}

// Round 11
// 7597.968 us; speedup vs baseline: 2.2097x; 2.2097x over previous
//
#include <hip/hip_runtime.h>

// CustomGRU: B=256, T=1024, I=128, H=256.  out = concat(output[B,T,H], h_last[B,H]) f32.
//
// R11 = R9 base (proven 4.43ms gru) + exchange redesign:
//  - per-WG flags (8/group x 2 parities) instead of per-thread version slots;
//    t<8 spin RELAXED then one ACQUIRE load (single L1-inv/step, not per poll).
//  - h payload = plain f32 [group][parity][batch8][unit256]; readers use NORMAL
//    float4 loads after the acquire (acquire invalidates the CU-shared L1).
//  - parity double-buffer: h(tg+1) overwrites h(tg-1) only after all flags(tg)
//    seen => every reader finished step tg-1 (same induction as R3-R10).
//  - out-stores staged in LDS -> coalesced float4 (R9 wrote 3x amplified).
// Matvec unchanged from R9: W slice 48 f32/thread in regs (asm-pinned, proven
// resident at VGPR=88), h in LDS kpad layout, DPP sum16 reduce.

#define B_SZ 256
#define T_SZ 1024
#define H_SZ 256
#define G3   768
#define NGRP 32
#define SPIN_MAX (1 << 27)

template<int CTRL>
__device__ __forceinline__ float dppadd(float x) {
    int v = __builtin_amdgcn_update_dpp(0, __float_as_int(x), CTRL, 0xF, 0xF, true);
    return x + __int_as_float(v);
}
__device__ __forceinline__ float sum16(float x) {
    x = dppadd<0xB1>(x);    // quad_perm xor1
    x = dppadd<0x4E>(x);    // quad_perm xor2
    x = dppadd<0x124>(x);   // row_ror:4
    x = dppadd<0x128>(x);   // row_ror:8
    return x;
}

static __device__ __forceinline__ int kpad(int k) { return k + 4 * (k >> 4); }

// ---------------- prep: xch <- h0 (both parities), flags <- 0 ----------------
__global__ void prep_kernel(const float* __restrict__ h0,
                            float* __restrict__ xch,
                            unsigned* __restrict__ flags) {
    int tid = blockIdx.x * blockDim.x + threadIdx.x;   // 65536
    if (tid < B_SZ * H_SZ) {
        int b = tid >> 8, u = tid & 255;
        int g = b >> 3, n = b & 7;
        float v = h0[tid];
        xch[((size_t)(g * 2 + 0) * 8 + n) * 256 + u] = v;
        xch[((size_t)(g * 2 + 1) * 8 + n) * 256 + u] = v;
    }
    if (tid < NGRP * 2 * 8) flags[tid] = 0u;
}

// ---------------- phase 1: gx = x @ W_ih^T (R9 kernel, unchanged) ----------------
__global__ __launch_bounds__(256) void gemm_x_kernel(
    const float* __restrict__ x, const float* __restrict__ wih,
    float* __restrict__ gx, int c, int tcShift)
{
    __shared__ __align__(16) float xs[64][132];
    __shared__ __align__(16) float ws[128][68];
    const int TC = 1 << tcShift;
    const int t  = threadIdx.x;
    const int bx = blockIdx.x, by = blockIdx.y;

#pragma unroll
    for (int i = 0; i < 8; ++i) {
        int f4 = t + i * 256;
        int r  = f4 >> 5, c4 = (f4 & 31) * 4;
        int rho = bx * 64 + r;
        int b = rho >> tcShift, u = rho & (TC - 1);
        float4 v = *(const float4*)(x + ((size_t)b * T_SZ + (size_t)c * TC + u) * 128 + c4);
        *(float4*)&xs[r][c4] = v;
    }

    const int gl = t & 31;
    const int rl = t >> 5;
    float acc[8][4];
#pragma unroll
    for (int i = 0; i < 8; ++i)
#pragma unroll
        for (int jj = 0; jj < 4; ++jj) acc[i][jj] = 0.f;

    for (int kb = 0; kb < 2; ++kb) {
        __syncthreads();
#pragma unroll
        for (int i = 0; i < 8; ++i) {
            int f4 = t + i * 256;
            int row = f4 >> 4, c4 = (f4 & 15) * 4;
            float4 v = *(const float4*)(wih + (size_t)(by * 128 + row) * 128 + kb * 64 + c4);
            *(float4*)&ws[row][c4] = v;
        }
        __syncthreads();

#pragma unroll 4
        for (int k4 = 0; k4 < 16; ++k4) {
            float4 wv0 = *(const float4*)&ws[gl     ][k4 * 4];
            float4 wv1 = *(const float4*)&ws[gl + 32][k4 * 4];
            float4 wv2 = *(const float4*)&ws[gl + 64][k4 * 4];
            float4 wv3 = *(const float4*)&ws[gl + 96][k4 * 4];
#pragma unroll
            for (int rr = 0; rr < 8; ++rr) {
                float4 xv = *(const float4*)&xs[rl + rr * 8][kb * 64 + k4 * 4];
                acc[rr][0] = fmaf(xv.w, wv0.w, fmaf(xv.z, wv0.z, fmaf(xv.y, wv0.y, fmaf(xv.x, wv0.x, acc[rr][0]))));
                acc[rr][1] = fmaf(xv.w, wv1.w, fmaf(xv.z, wv1.z, fmaf(xv.y, wv1.y, fmaf(xv.x, wv1.x, acc[rr][1]))));
                acc[rr][2] = fmaf(xv.w, wv2.w, fmaf(xv.z, wv2.z, fmaf(xv.y, wv2.y, fmaf(xv.x, wv2.x, acc[rr][2]))));
                acc[rr][3] = fmaf(xv.w, wv3.w, fmaf(xv.z, wv3.z, fmaf(xv.y, wv3.y, fmaf(xv.x, wv3.x, acc[rr][3]))));
            }
        }
    }

#pragma unroll
    for (int rr = 0; rr < 8; ++rr) {
        size_t base = (size_t)(bx * 64 + rl + rr * 8) * G3 + by * 128 + gl;
#pragma unroll
        for (int gi = 0; gi < 4; ++gi)
            gx[base + 32 * gi] = acc[rr][gi];
    }
}

// ---- 16-elem dot (all float4, static) ----
__device__ __forceinline__ float d16(float a,
    const float4& W0, const float4& W1, const float4& W2, const float4& W3,
    const float4& H0, const float4& H1, const float4& H2, const float4& H3) {
    a = fmaf(W0.x, H0.x, a); a = fmaf(W0.y, H0.y, a); a = fmaf(W0.z, H0.z, a); a = fmaf(W0.w, H0.w, a);
    a = fmaf(W1.x, H1.x, a); a = fmaf(W1.y, H1.y, a); a = fmaf(W1.z, H1.z, a); a = fmaf(W1.w, H1.w, a);
    a = fmaf(W2.x, H2.x, a); a = fmaf(W2.y, H2.y, a); a = fmaf(W2.z, H2.z, a); a = fmaf(W2.w, H2.w, a);
    a = fmaf(W3.x, H3.x, a); a = fmaf(W3.y, H3.y, a); a = fmaf(W3.z, H3.z, a); a = fmaf(W3.w, H3.w, a);
    return a;
}

#define PIN4(v) asm volatile("" : "+v"(v.x), "+v"(v.y), "+v"(v.z), "+v"(v.w));

// ---------------- phase 2: recurrence ----------------
// grid 256 x 512. g = bid&31 (group; all 8 members share bid mod 8 -> same XCD),
// w = bid>>5, u0 = 32w. Thread: j = t>>4 (unit), p = t&15 (16-k slice).
__global__ __launch_bounds__(512) void gru_kernel(
    const float* __restrict__ gx, const float* __restrict__ whh,
    const float* __restrict__ bih, const float* __restrict__ bhh,
    float* __restrict__ xch, unsigned* __restrict__ flags,
    float* __restrict__ out, int gbase, int tc, int isLast)
{
    __shared__ __align__(16) float hl[8][320];   // h, kpad layout
    __shared__ __align__(16) float hst[8][32];   // out-staging

    const int t   = threadIdx.x;
    const int bid = blockIdx.x;
    const int g   = bid & 31;
    const int w   = bid >> 5;
    const int u0  = w * 32;
    const int j   = t >> 4;
    const int p   = t & 15;
    const int uj  = u0 + j;

    // ---- W slice -> 12 named float4 registers (proven resident) ----
    const float* wr0 = whh + (size_t)(uj)       * H_SZ + p * 16;
    const float* wr1 = whh + (size_t)(256 + uj) * H_SZ + p * 16;
    const float* wr2 = whh + (size_t)(512 + uj) * H_SZ + p * 16;
    float4 w00 = *(const float4*)(wr0 + 0), w01 = *(const float4*)(wr0 + 4),
           w02 = *(const float4*)(wr0 + 8), w03 = *(const float4*)(wr0 + 12);
    float4 w10 = *(const float4*)(wr1 + 0), w11 = *(const float4*)(wr1 + 4),
           w12 = *(const float4*)(wr1 + 8), w13 = *(const float4*)(wr1 + 12);
    float4 w20 = *(const float4*)(wr2 + 0), w21 = *(const float4*)(wr2 + 4),
           w22 = *(const float4*)(wr2 + 8), w23 = *(const float4*)(wr2 + 12);
    PIN4(w00) PIN4(w01) PIN4(w02) PIN4(w03)
    PIN4(w10) PIN4(w11) PIN4(w12) PIN4(w13)
    PIN4(w20) PIN4(w21) PIN4(w22) PIN4(w23)

    const float bsr = bih[uj]       + bhh[uj];
    const float bsz = bih[256 + uj] + bhh[256 + uj];
    const float bsn = bih[512 + uj] + bhh[512 + uj];

    const float* gxp = (p < 8) ? gx + ((size_t)(8 * g + p) * tc) * G3 + uj : nullptr;

    // gather mapping: thread loads 1 float4 of the 8KB block
    const int n_g = t >> 6;                 // batch row 0..7 (== wave id)
    const int uu  = (t & 63) * 4;           // unit base 0..252
    const int kc  = uu + (((t & 63) >> 2) << 2);   // kpad(uu)
    const int kuj = kpad(uj);
    // out-stage mapping (t<64): row no_, 4-unit chunk q_
    const int no_ = t >> 3, q_ = t & 7;

    unsigned* flbase = flags + (size_t)g * 16;       // [par][w8]

#pragma unroll 1
    for (int u = 0; u < tc; ++u) {
        const int tg  = gbase + u;
        const int par = tg & 1;

        // ---- wait: 8 flags (t<8), RELAXED spin + one ACQUIRE ----
        if (t < 8) {
            unsigned* fp = flbase + par * 8 + t;
            unsigned v = __hip_atomic_load(fp, __ATOMIC_RELAXED, __HIP_MEMORY_SCOPE_AGENT);
            int sp = 0;
            while (v < (unsigned)tg && sp < SPIN_MAX) {
                __builtin_amdgcn_s_sleep(2);
                v = __hip_atomic_load(fp, __ATOMIC_RELAXED, __HIP_MEMORY_SCOPE_AGENT);
                ++sp;
            }
            (void)__hip_atomic_load(fp, __ATOMIC_ACQUIRE, __HIP_MEMORY_SCOPE_AGENT);
        }
        __syncthreads();   // flag seen + L1 invalidated; hst(u-1) stable; hl reads done

        // ---- coalesced out-store for step u-1 ----
        if (u > 0 && t < 64) {
            float4 o;
            o.x = hst[no_][q_ * 4]; o.y = hst[no_][q_ * 4 + 1];
            o.z = hst[no_][q_ * 4 + 2]; o.w = hst[no_][q_ * 4 + 3];
            *(float4*)(out + ((size_t)(8 * g + no_) * T_SZ + (tg - 1)) * H_SZ + u0 + q_ * 4) = o;
        }

        // ---- gx for this step (global; latency hides under gather+barrier) ----
        float gxr = 0.f, gxz = 0.f, gxn = 0.f;
        if (p < 8) {
            size_t go = (size_t)u * G3;
            gxr = gxp[go]; gxz = gxp[go + 256]; gxn = gxp[go + 512];
        }

        // ---- bulk gather: 8KB via normal float4 loads -> LDS ----
        {
            const float* xb = xch + (size_t)(g * 2 + par) * 8 * 256;
            float4 hv = *(const float4*)(xb + (size_t)t * 4);
            *(float4*)&hl[n_g][kc] = hv;
        }
        __syncthreads();

        // ---- matvec: W regs x h LDS ----
        float acc0[8], acc1[8], acc2[8];
        const float* hbp = &hl[0][0] + p * 20;
#pragma unroll
        for (int n = 0; n < 8; ++n) {
            const float* hr = hbp + n * 320;
            float4 h0 = *(const float4*)(hr);
            float4 h1 = *(const float4*)(hr + 4);
            float4 h2 = *(const float4*)(hr + 8);
            float4 h3 = *(const float4*)(hr + 12);
            acc0[n] = d16(0.f, w00, w01, w02, w03, h0, h1, h2, h3);
            acc1[n] = d16(0.f, w10, w11, w12, w13, h0, h1, h2, h3);
            acc2[n] = d16(0.f, w20, w21, w22, w23, h0, h1, h2, h3);
        }

        // ---- 16-lane reduce; keep the n==p triple ----
        float sr = 0.f, sz = 0.f, sn = 0.f;
#pragma unroll
        for (int n = 0; n < 8; ++n) {
            float v0 = sum16(acc0[n]);
            float v1 = sum16(acc1[n]);
            float v2 = sum16(acc2[n]);
            if (p == n) { sr = v0; sz = v1; sn = v2; }
        }

        // ---- gates + publish (p<8, batch n=p) ----
        if (p < 8) {
            float hold = hl[p][kuj];
            float ar = sr + gxr + bsr;
            float az = sz + gxz + bsz;
            float an = sn + gxn + bsn;
            float r  = 1.f / (1.f + expf(-ar));
            float z  = 1.f / (1.f + expf(-az));
            float nn = tanhf(r * an);
            float hn = (1.f - z) * hold + z * nn;

            hst[p][j] = hn;
            __hip_atomic_store(
                xch + (size_t)(g * 2 + ((tg + 1) & 1)) * 8 * 256 + (size_t)p * 256 + uj,
                hn, __ATOMIC_RELAXED, __HIP_MEMORY_SCOPE_AGENT);
        }
        __syncthreads();   // drains publish stores (vmcnt0) before flag; hst visible
        if (t == 0) {
            __hip_atomic_store(flbase + ((tg + 1) & 1) * 8 + w, (unsigned)(tg + 1),
                               __ATOMIC_RELEASE, __HIP_MEMORY_SCOPE_AGENT);
        }
    }

    // ---- flush last step's out row (+ h_last) ----
    if (t < 64) {
        float4 o;
        o.x = hst[no_][q_ * 4]; o.y = hst[no_][q_ * 4 + 1];
        o.z = hst[no_][q_ * 4 + 2]; o.w = hst[no_][q_ * 4 + 3];
        *(float4*)(out + ((size_t)(8 * g + no_) * T_SZ + (gbase + tc - 1)) * H_SZ + u0 + q_ * 4) = o;
        if (isLast)
            *(float4*)(out + (size_t)B_SZ * T_SZ * H_SZ
                           + (size_t)(8 * g + no_) * H_SZ + u0 + q_ * 4) = o;
    }
}

// ---------------- host ----------------
extern "C" void kernel_launch(void* const* d_in, const int* in_sizes, int n_in,
                              void* d_out, int out_size, void* d_ws, size_t ws_size,
                              hipStream_t stream) {
    const float* x   = (const float*)d_in[0];
    const float* h0  = (const float*)d_in[1];
    const float* wih = (const float*)d_in[2];
    const float* whh = (const float*)d_in[3];
    const float* bih = (const float*)d_in[4];
    const float* bhh = (const float*)d_in[5];
    float* out = (float*)d_out;

    char* ws = (char*)d_ws;
    const size_t xchB  = (size_t)NGRP * 2 * 8 * 256 * 4;   // 512 KiB
    const size_t flagB = 4096;
    float*    xch   = (float*)ws;
    unsigned* flags = (unsigned*)(ws + xchB);
    float*    gxb   = (float*)(ws + xchB + flagB);

    int tcShift = 10;
    while (tcShift > 0 &&
           xchB + flagB + (786432ull << tcShift) > ws_size) --tcShift;
    const int TC  = 1 << tcShift;
    const int nCh = T_SZ / TC;

    prep_kernel<<<dim3(256), dim3(256), 0, stream>>>(h0, xch, flags);
    for (int c = 0; c < nCh; ++c) {
        gemm_x_kernel<<<dim3(B_SZ * TC / 64, 6), dim3(256), 0, stream>>>(
            x, wih, gxb, c, tcShift);
        gru_kernel<<<dim3(B_SZ), dim3(512), 0, stream>>>(
            gxb, whh, bih, bhh, xch, flags, out, c * TC, TC, (c == nCh - 1) ? 1 : 0);
    }
}

// Round 12
// 7203.123 us; speedup vs baseline: 2.3308x; 1.0548x over previous
//
#include <hip/hip_runtime.h>

// CustomGRU: B=256, T=1024, I=128, H=256.  out = concat(output[B,T,H], h_last[B,H]) f32.
//
// R12 = R11 exchange design + fixes:
//  1. amdgpu_waves_per_eu(2,2) RESTORED on gru (R11 dropped it -> VGPR capped at 64,
//     48 pinned W floats evicted, W re-fetched from L2 every step, 7.0ms).
//  2. Butterfly reduce (xor8 row_ror / xor2,xor1 quad_perm keep+send / xor4
//     ds_swizzle): lane p ends with its own n=p&7 gate triple; ~85 fewer VALU
//     inst/thread/step than sum16+selects.
//  3. gx prefetched one step ahead (registers), hiding HBM latency under matvec.
// Exchange: per-WG flags (t<8 spin RELAXED + one ACQUIRE), plain f32 h payload,
// parity double-buffer (R3-proven induction). Out-stores staged in LDS -> float4.

#define B_SZ 256
#define T_SZ 1024
#define H_SZ 256
#define G3   768
#define NGRP 32
#define SPIN_MAX (1 << 27)

template<int CTRL>
__device__ __forceinline__ float dppx(float s) {
    return __int_as_float(
        __builtin_amdgcn_update_dpp(0, __float_as_int(s), CTRL, 0xF, 0xF, true));
}
__device__ __forceinline__ float swz4(float s) {
    return __int_as_float(__builtin_amdgcn_ds_swizzle(__float_as_int(s), 0x101F));
}

static __device__ __forceinline__ int kpad(int k) { return k + 4 * (k >> 4); }

// ---------------- prep: xch <- h0 (both parities), flags <- 0 ----------------
__global__ void prep_kernel(const float* __restrict__ h0,
                            float* __restrict__ xch,
                            unsigned* __restrict__ flags) {
    int tid = blockIdx.x * blockDim.x + threadIdx.x;
    if (tid < B_SZ * H_SZ) {
        int b = tid >> 8, u = tid & 255;
        int g = b >> 3, n = b & 7;
        float v = h0[tid];
        xch[((size_t)(g * 2 + 0) * 8 + n) * 256 + u] = v;
        xch[((size_t)(g * 2 + 1) * 8 + n) * 256 + u] = v;
    }
    if (tid < NGRP * 2 * 8) flags[tid] = 0u;
}

// ---------------- phase 1: gx = x @ W_ih^T (unchanged) ----------------
__global__ __launch_bounds__(256) void gemm_x_kernel(
    const float* __restrict__ x, const float* __restrict__ wih,
    float* __restrict__ gx, int c, int tcShift)
{
    __shared__ __align__(16) float xs[64][132];
    __shared__ __align__(16) float ws[128][68];
    const int TC = 1 << tcShift;
    const int t  = threadIdx.x;
    const int bx = blockIdx.x, by = blockIdx.y;

#pragma unroll
    for (int i = 0; i < 8; ++i) {
        int f4 = t + i * 256;
        int r  = f4 >> 5, c4 = (f4 & 31) * 4;
        int rho = bx * 64 + r;
        int b = rho >> tcShift, u = rho & (TC - 1);
        float4 v = *(const float4*)(x + ((size_t)b * T_SZ + (size_t)c * TC + u) * 128 + c4);
        *(float4*)&xs[r][c4] = v;
    }

    const int gl = t & 31;
    const int rl = t >> 5;
    float acc[8][4];
#pragma unroll
    for (int i = 0; i < 8; ++i)
#pragma unroll
        for (int jj = 0; jj < 4; ++jj) acc[i][jj] = 0.f;

    for (int kb = 0; kb < 2; ++kb) {
        __syncthreads();
#pragma unroll
        for (int i = 0; i < 8; ++i) {
            int f4 = t + i * 256;
            int row = f4 >> 4, c4 = (f4 & 15) * 4;
            float4 v = *(const float4*)(wih + (size_t)(by * 128 + row) * 128 + kb * 64 + c4);
            *(float4*)&ws[row][c4] = v;
        }
        __syncthreads();

#pragma unroll 4
        for (int k4 = 0; k4 < 16; ++k4) {
            float4 wv0 = *(const float4*)&ws[gl     ][k4 * 4];
            float4 wv1 = *(const float4*)&ws[gl + 32][k4 * 4];
            float4 wv2 = *(const float4*)&ws[gl + 64][k4 * 4];
            float4 wv3 = *(const float4*)&ws[gl + 96][k4 * 4];
#pragma unroll
            for (int rr = 0; rr < 8; ++rr) {
                float4 xv = *(const float4*)&xs[rl + rr * 8][kb * 64 + k4 * 4];
                acc[rr][0] = fmaf(xv.w, wv0.w, fmaf(xv.z, wv0.z, fmaf(xv.y, wv0.y, fmaf(xv.x, wv0.x, acc[rr][0]))));
                acc[rr][1] = fmaf(xv.w, wv1.w, fmaf(xv.z, wv1.z, fmaf(xv.y, wv1.y, fmaf(xv.x, wv1.x, acc[rr][1]))));
                acc[rr][2] = fmaf(xv.w, wv2.w, fmaf(xv.z, wv2.z, fmaf(xv.y, wv2.y, fmaf(xv.x, wv2.x, acc[rr][2]))));
                acc[rr][3] = fmaf(xv.w, wv3.w, fmaf(xv.z, wv3.z, fmaf(xv.y, wv3.y, fmaf(xv.x, wv3.x, acc[rr][3]))));
            }
        }
    }

#pragma unroll
    for (int rr = 0; rr < 8; ++rr) {
        size_t base = (size_t)(bx * 64 + rl + rr * 8) * G3 + by * 128 + gl;
#pragma unroll
        for (int gi = 0; gi < 4; ++gi)
            gx[base + 32 * gi] = acc[rr][gi];
    }
}

// ---- 16-elem dot ----
__device__ __forceinline__ float d16(float a,
    const float4& W0, const float4& W1, const float4& W2, const float4& W3,
    const float4& H0, const float4& H1, const float4& H2, const float4& H3) {
    a = fmaf(W0.x, H0.x, a); a = fmaf(W0.y, H0.y, a); a = fmaf(W0.z, H0.z, a); a = fmaf(W0.w, H0.w, a);
    a = fmaf(W1.x, H1.x, a); a = fmaf(W1.y, H1.y, a); a = fmaf(W1.z, H1.z, a); a = fmaf(W1.w, H1.w, a);
    a = fmaf(W2.x, H2.x, a); a = fmaf(W2.y, H2.y, a); a = fmaf(W2.z, H2.z, a); a = fmaf(W2.w, H2.w, a);
    a = fmaf(W3.x, H3.x, a); a = fmaf(W3.y, H3.y, a); a = fmaf(W3.z, H3.z, a); a = fmaf(W3.w, H3.w, a);
    return a;
}

#define PIN4(v) asm volatile("" : "+v"(v.x), "+v"(v.y), "+v"(v.z), "+v"(v.w));

// ---------------- phase 2: recurrence ----------------
__global__ __launch_bounds__(512)
__attribute__((amdgpu_waves_per_eu(2, 2)))
void gru_kernel(
    const float* __restrict__ gx, const float* __restrict__ whh,
    const float* __restrict__ bih, const float* __restrict__ bhh,
    float* __restrict__ xch, unsigned* __restrict__ flags,
    float* __restrict__ out, int gbase, int tc, int isLast)
{
    __shared__ __align__(16) float hl[8][320];
    __shared__ __align__(16) float hst[8][32];

    const int t   = threadIdx.x;
    const int bid = blockIdx.x;
    const int g   = bid & 31;
    const int w   = bid >> 5;
    const int u0  = w * 32;
    const int j   = t >> 4;
    const int p   = t & 15;
    const int uj  = u0 + j;

    // ---- W slice -> 12 named float4 registers ----
    const float* wr0 = whh + (size_t)(uj)       * H_SZ + p * 16;
    const float* wr1 = whh + (size_t)(256 + uj) * H_SZ + p * 16;
    const float* wr2 = whh + (size_t)(512 + uj) * H_SZ + p * 16;
    float4 w00 = *(const float4*)(wr0 + 0), w01 = *(const float4*)(wr0 + 4),
           w02 = *(const float4*)(wr0 + 8), w03 = *(const float4*)(wr0 + 12);
    float4 w10 = *(const float4*)(wr1 + 0), w11 = *(const float4*)(wr1 + 4),
           w12 = *(const float4*)(wr1 + 8), w13 = *(const float4*)(wr1 + 12);
    float4 w20 = *(const float4*)(wr2 + 0), w21 = *(const float4*)(wr2 + 4),
           w22 = *(const float4*)(wr2 + 8), w23 = *(const float4*)(wr2 + 12);
    PIN4(w00) PIN4(w01) PIN4(w02) PIN4(w03)
    PIN4(w10) PIN4(w11) PIN4(w12) PIN4(w13)
    PIN4(w20) PIN4(w21) PIN4(w22) PIN4(w23)

    const float bsr = bih[uj]       + bhh[uj];
    const float bsz = bih[256 + uj] + bhh[256 + uj];
    const float bsn = bih[512 + uj] + bhh[512 + uj];

    const float* gxp = (p < 8) ? gx + ((size_t)(8 * g + p) * tc) * G3 + uj : nullptr;

    const int n_g = t >> 6;
    const int uu  = (t & 63) * 4;
    const int kc  = uu + (((t & 63) >> 2) << 2);
    const int kuj = kpad(uj);
    const int no_ = t >> 3, q_ = t & 7;

    unsigned* flbase = flags + (size_t)g * 16;

    // preload gx(u=0)
    float gxr = 0.f, gxz = 0.f, gxn = 0.f;
    if (p < 8) { gxr = gxp[0]; gxz = gxp[256]; gxn = gxp[512]; }

    const bool b0 = (p & 1) != 0, b1 = (p & 2) != 0, b2 = (p & 4) != 0;

#pragma unroll 1
    for (int u = 0; u < tc; ++u) {
        const int tg  = gbase + u;
        const int par = tg & 1;

        if (t < 8) {
            unsigned* fp = flbase + par * 8 + t;
            unsigned v = __hip_atomic_load(fp, __ATOMIC_RELAXED, __HIP_MEMORY_SCOPE_AGENT);
            int sp = 0;
            while (v < (unsigned)tg && sp < SPIN_MAX) {
                __builtin_amdgcn_s_sleep(2);
                v = __hip_atomic_load(fp, __ATOMIC_RELAXED, __HIP_MEMORY_SCOPE_AGENT);
                ++sp;
            }
            (void)__hip_atomic_load(fp, __ATOMIC_ACQUIRE, __HIP_MEMORY_SCOPE_AGENT);
        }
        __syncthreads();

        // coalesced out-store for step u-1
        if (u > 0 && t < 64) {
            float4 o;
            o.x = hst[no_][q_ * 4]; o.y = hst[no_][q_ * 4 + 1];
            o.z = hst[no_][q_ * 4 + 2]; o.w = hst[no_][q_ * 4 + 3];
            *(float4*)(out + ((size_t)(8 * g + no_) * T_SZ + (tg - 1)) * H_SZ + u0 + q_ * 4) = o;
        }

        // bulk gather: 8KB via normal float4 loads -> LDS
        {
            const float* xb = xch + (size_t)(g * 2 + par) * 8 * 256;
            float4 hv = *(const float4*)(xb + (size_t)t * 4);
            *(float4*)&hl[n_g][kc] = hv;
        }
        __syncthreads();

        // prefetch gx(u+1) (consumed next iteration; hides under matvec+reduce)
        float pgr = 0.f, pgz = 0.f, pgn = 0.f;
        if (p < 8 && u + 1 < tc) {
            size_t go = (size_t)(u + 1) * G3;
            pgr = gxp[go]; pgz = gxp[go + 256]; pgn = gxp[go + 512];
        }

        // ---- matvec: W regs x h LDS ----
        float acc0[8], acc1[8], acc2[8];
        const float* hbp = &hl[0][0] + p * 20;
#pragma unroll
        for (int n = 0; n < 8; ++n) {
            const float* hr = hbp + n * 320;
            float4 h0 = *(const float4*)(hr);
            float4 h1 = *(const float4*)(hr + 4);
            float4 h2 = *(const float4*)(hr + 8);
            float4 h3 = *(const float4*)(hr + 12);
            acc0[n] = d16(0.f, w00, w01, w02, w03, h0, h1, h2, h3);
            acc1[n] = d16(0.f, w10, w11, w12, w13, h0, h1, h2, h3);
            acc2[n] = d16(0.f, w20, w21, w22, w23, h0, h1, h2, h3);
        }

        // ---- butterfly reduce: lane p ends with sums for n = p&7 ----
        // xor8 (row_ror:8 == xor8 within 16-lane rows)
#pragma unroll
        for (int n = 0; n < 8; ++n) {
            acc0[n] += dppx<0x128>(acc0[n]);
            acc1[n] += dppx<0x128>(acc1[n]);
            acc2[n] += dppx<0x128>(acc2[n]);
        }
        // xor2: keep n with bit1(n)==bit1(p); exchange discarded half
        float k0[4], k1[4], k2[4];
#pragma unroll
        for (int i = 0; i < 4; ++i) {
            const int nlo = (i & 1) | ((i >> 1) << 2);
            const int nhi = nlo | 2;
            float K, S;
            K = b1 ? acc0[nhi] : acc0[nlo]; S = b1 ? acc0[nlo] : acc0[nhi];
            k0[i] = K + dppx<0x4E>(S);
            K = b1 ? acc1[nhi] : acc1[nlo]; S = b1 ? acc1[nlo] : acc1[nhi];
            k1[i] = K + dppx<0x4E>(S);
            K = b1 ? acc2[nhi] : acc2[nlo]; S = b1 ? acc2[nlo] : acc2[nhi];
            k2[i] = K + dppx<0x4E>(S);
        }
        // xor1: keep bit0(n)==bit0(p)   (k[i] holds n = (i&1)|(b1<<1)|((i>>1)<<2))
        float m0[2], m1[2], m2[2];
#pragma unroll
        for (int i = 0; i < 2; ++i) {
            float K, S;
            K = b0 ? k0[2*i+1] : k0[2*i]; S = b0 ? k0[2*i] : k0[2*i+1];
            m0[i] = K + dppx<0xB1>(S);
            K = b0 ? k1[2*i+1] : k1[2*i]; S = b0 ? k1[2*i] : k1[2*i+1];
            m1[i] = K + dppx<0xB1>(S);
            K = b0 ? k2[2*i+1] : k2[2*i]; S = b0 ? k2[2*i] : k2[2*i+1];
            m2[i] = K + dppx<0xB1>(S);
        }
        // xor4 via ds_swizzle: keep bit2(n)==bit2(p)   (m[i] holds n = b0|(b1<<1)|(i<<2))
        float K0 = b2 ? m0[1] : m0[0], S0 = b2 ? m0[0] : m0[1];
        float K1 = b2 ? m1[1] : m1[0], S1 = b2 ? m1[0] : m1[1];
        float K2 = b2 ? m2[1] : m2[0], S2 = b2 ? m2[0] : m2[1];
        float sr = K0 + swz4(S0);
        float sz = K1 + swz4(S1);
        float sn = K2 + swz4(S2);

        // ---- gates + publish (p<8, batch n=p) ----
        if (p < 8) {
            float hold = hl[p][kuj];
            float ar = sr + gxr + bsr;
            float az = sz + gxz + bsz;
            float an = sn + gxn + bsn;
            float r  = 1.f / (1.f + expf(-ar));
            float z  = 1.f / (1.f + expf(-az));
            float nn = tanhf(r * an);
            float hn = (1.f - z) * hold + z * nn;

            hst[p][j] = hn;
            __hip_atomic_store(
                xch + (size_t)(g * 2 + ((tg + 1) & 1)) * 8 * 256 + (size_t)p * 256 + uj,
                hn, __ATOMIC_RELAXED, __HIP_MEMORY_SCOPE_AGENT);
        }
        gxr = pgr; gxz = pgz; gxn = pgn;
        __syncthreads();   // drains publish stores before flag; hst visible
        if (t == 0) {
            __hip_atomic_store(flbase + ((tg + 1) & 1) * 8 + w, (unsigned)(tg + 1),
                               __ATOMIC_RELEASE, __HIP_MEMORY_SCOPE_AGENT);
        }
    }

    // ---- flush last step's out row (+ h_last) ----
    if (t < 64) {
        float4 o;
        o.x = hst[no_][q_ * 4]; o.y = hst[no_][q_ * 4 + 1];
        o.z = hst[no_][q_ * 4 + 2]; o.w = hst[no_][q_ * 4 + 3];
        *(float4*)(out + ((size_t)(8 * g + no_) * T_SZ + (gbase + tc - 1)) * H_SZ + u0 + q_ * 4) = o;
        if (isLast)
            *(float4*)(out + (size_t)B_SZ * T_SZ * H_SZ
                           + (size_t)(8 * g + no_) * H_SZ + u0 + q_ * 4) = o;
    }
}

// ---------------- host ----------------
extern "C" void kernel_launch(void* const* d_in, const int* in_sizes, int n_in,
                              void* d_out, int out_size, void* d_ws, size_t ws_size,
                              hipStream_t stream) {
    const float* x   = (const float*)d_in[0];
    const float* h0  = (const float*)d_in[1];
    const float* wih = (const float*)d_in[2];
    const float* whh = (const float*)d_in[3];
    const float* bih = (const float*)d_in[4];
    const float* bhh = (const float*)d_in[5];
    float* out = (float*)d_out;

    char* ws = (char*)d_ws;
    const size_t xchB  = (size_t)NGRP * 2 * 8 * 256 * 4;   // 512 KiB
    const size_t flagB = 4096;
    float*    xch   = (float*)ws;
    unsigned* flags = (unsigned*)(ws + xchB);
    float*    gxb   = (float*)(ws + xchB + flagB);

    int tcShift = 10;
    while (tcShift > 0 &&
           xchB + flagB + (786432ull << tcShift) > ws_size) --tcShift;
    const int TC  = 1 << tcShift;
    const int nCh = T_SZ / TC;

    prep_kernel<<<dim3(256), dim3(256), 0, stream>>>(h0, xch, flags);
    for (int c = 0; c < nCh; ++c) {
        gemm_x_kernel<<<dim3(B_SZ * TC / 64, 6), dim3(256), 0, stream>>>(
            x, wih, gxb, c, tcShift);
        gru_kernel<<<dim3(B_SZ), dim3(512), 0, stream>>>(
            gxb, whh, bih, bhh, xch, flags, out, c * TC, TC, (c == nCh - 1) ? 1 : 0);
    }
}

// Round 13
// 4005.631 us; speedup vs baseline: 4.1914x; 1.7982x over previous
//
#include <hip/hip_runtime.h>

// CustomGRU: B=256, T=1024, I=128, H=256.  out = concat(output[B,T,H], h_last[B,H]) f32.
//
// R13: back to R9's packed-u64 exchange (data travels WITH the version word -> one
// L2 RTT per step; R11/R12's flag+gather serialized two RTTs and regressed).
// New compute shape: thread owns 2 units x 3 gates x 8-k slice (48 W f32 = proven
// register-resident size) -> 16 ds_read_b128 per step (was 32). 32-lane keep/send
// butterfly reduce (quad_perm xor1/2, ds_swizzle xor4/16, row_ror:8 xor8).
// 8-WG groups (same-XCD), parity double-buffered slots, bounded spins.

#define B_SZ 256
#define T_SZ 1024
#define H_SZ 256
#define G3   768
#define NGRP 32
#define SPIN_MAX (1 << 27)

template<int CTRL>
__device__ __forceinline__ float dppx(float s) {
    return __int_as_float(
        __builtin_amdgcn_update_dpp(0, __float_as_int(s), CTRL, 0xF, 0xF, true));
}
template<int MASK>
__device__ __forceinline__ float swzx(float s) {
    return __int_as_float(__builtin_amdgcn_ds_swizzle(__float_as_int(s), MASK));
}

static __device__ __forceinline__ int kpad(int k) { return k + 4 * (k >> 4); }

// slot: [g 32][par 2][n 8][unit 256] u64 = (ver<<32)|f32bits
static __device__ __forceinline__ size_t xsl(int g, int par, int n, int u) {
    return (((size_t)g * 2 + par) * 8 + n) * 256 + u;
}

// ---------------- prep ----------------
__global__ void prep_kernel(const float* __restrict__ h0,
                            unsigned long long* __restrict__ xch) {
    int tid = blockIdx.x * blockDim.x + threadIdx.x;
    if (tid < B_SZ * H_SZ) {
        int b = tid >> 8, u = tid & 255;
        int g = b >> 3, n = b & 7;
        unsigned long long val = (unsigned long long)__float_as_uint(h0[tid]);
        xch[xsl(g, 0, n, u)] = val;
        xch[xsl(g, 1, n, u)] = val;
    }
}

// ---------------- phase 1: gx = x @ W_ih^T (unchanged since R9) ----------------
__global__ __launch_bounds__(256) void gemm_x_kernel(
    const float* __restrict__ x, const float* __restrict__ wih,
    float* __restrict__ gx, int c, int tcShift)
{
    __shared__ __align__(16) float xs[64][132];
    __shared__ __align__(16) float ws[128][68];
    const int TC = 1 << tcShift;
    const int t  = threadIdx.x;
    const int bx = blockIdx.x, by = blockIdx.y;

#pragma unroll
    for (int i = 0; i < 8; ++i) {
        int f4 = t + i * 256;
        int r  = f4 >> 5, c4 = (f4 & 31) * 4;
        int rho = bx * 64 + r;
        int b = rho >> tcShift, u = rho & (TC - 1);
        float4 v = *(const float4*)(x + ((size_t)b * T_SZ + (size_t)c * TC + u) * 128 + c4);
        *(float4*)&xs[r][c4] = v;
    }

    const int gl = t & 31;
    const int rl = t >> 5;
    float acc[8][4];
#pragma unroll
    for (int i = 0; i < 8; ++i)
#pragma unroll
        for (int jj = 0; jj < 4; ++jj) acc[i][jj] = 0.f;

    for (int kb = 0; kb < 2; ++kb) {
        __syncthreads();
#pragma unroll
        for (int i = 0; i < 8; ++i) {
            int f4 = t + i * 256;
            int row = f4 >> 4, c4 = (f4 & 15) * 4;
            float4 v = *(const float4*)(wih + (size_t)(by * 128 + row) * 128 + kb * 64 + c4);
            *(float4*)&ws[row][c4] = v;
        }
        __syncthreads();

#pragma unroll 4
        for (int k4 = 0; k4 < 16; ++k4) {
            float4 wv0 = *(const float4*)&ws[gl     ][k4 * 4];
            float4 wv1 = *(const float4*)&ws[gl + 32][k4 * 4];
            float4 wv2 = *(const float4*)&ws[gl + 64][k4 * 4];
            float4 wv3 = *(const float4*)&ws[gl + 96][k4 * 4];
#pragma unroll
            for (int rr = 0; rr < 8; ++rr) {
                float4 xv = *(const float4*)&xs[rl + rr * 8][kb * 64 + k4 * 4];
                acc[rr][0] = fmaf(xv.w, wv0.w, fmaf(xv.z, wv0.z, fmaf(xv.y, wv0.y, fmaf(xv.x, wv0.x, acc[rr][0]))));
                acc[rr][1] = fmaf(xv.w, wv1.w, fmaf(xv.z, wv1.z, fmaf(xv.y, wv1.y, fmaf(xv.x, wv1.x, acc[rr][1]))));
                acc[rr][2] = fmaf(xv.w, wv2.w, fmaf(xv.z, wv2.z, fmaf(xv.y, wv2.y, fmaf(xv.x, wv2.x, acc[rr][2]))));
                acc[rr][3] = fmaf(xv.w, wv3.w, fmaf(xv.z, wv3.z, fmaf(xv.y, wv3.y, fmaf(xv.x, wv3.x, acc[rr][3]))));
            }
        }
    }

#pragma unroll
    for (int rr = 0; rr < 8; ++rr) {
        size_t base = (size_t)(bx * 64 + rl + rr * 8) * G3 + by * 128 + gl;
#pragma unroll
        for (int gi = 0; gi < 4; ++gi)
            gx[base + 32 * gi] = acc[rr][gi];
    }
}

// ---- 8-elem dot: acc += (Wl,Wh) . (H0,H1) ----
__device__ __forceinline__ float d8(float a, const float4& Wl, const float4& Wh,
                                    const float4& H0, const float4& H1) {
    a = fmaf(Wl.x, H0.x, a); a = fmaf(Wl.y, H0.y, a);
    a = fmaf(Wl.z, H0.z, a); a = fmaf(Wl.w, H0.w, a);
    a = fmaf(Wh.x, H1.x, a); a = fmaf(Wh.y, H1.y, a);
    a = fmaf(Wh.z, H1.z, a); a = fmaf(Wh.w, H1.w, a);
    return a;
}

#define PIN4(v) asm volatile("" : "+v"(v.x), "+v"(v.y), "+v"(v.z), "+v"(v.w));

// ---------------- phase 2: recurrence ----------------
// grid 256 x 512. g = bid&31, w = bid>>5, u0 = 32w (8 WGs/group, same XCD).
// Thread: j2 = t>>5 (unit pair), p = t&31 (8-k slice). Units ua=u0+2*j2, ub=ua+1.
__global__ __launch_bounds__(512)
__attribute__((amdgpu_waves_per_eu(2, 2)))
void gru_kernel(
    const float* __restrict__ gx, const float* __restrict__ whh,
    const float* __restrict__ bih, const float* __restrict__ bhh,
    unsigned long long* __restrict__ xch, float* __restrict__ out,
    int gbase, int tc, int isLast)
{
    __shared__ __align__(16) float hl[8][320];
    __shared__ __align__(16) float hst[8][32];

    const int t   = threadIdx.x;
    const int bid = blockIdx.x;
    const int g   = bid & 31;
    const int w   = bid >> 5;
    const int u0  = w * 32;
    const int j2  = t >> 5;
    const int p   = t & 31;
    const int ua  = u0 + 2 * j2;
    const int ub  = ua + 1;
    const int k0  = 8 * p;

    // ---- W: 2 units x 3 gates x 8 k = 12 named float4 (proven-resident size) ----
    float4 a0l = *(const float4*)(whh + (size_t)(ua)       * H_SZ + k0);
    float4 a0h = *(const float4*)(whh + (size_t)(ua)       * H_SZ + k0 + 4);
    float4 a1l = *(const float4*)(whh + (size_t)(256 + ua) * H_SZ + k0);
    float4 a1h = *(const float4*)(whh + (size_t)(256 + ua) * H_SZ + k0 + 4);
    float4 a2l = *(const float4*)(whh + (size_t)(512 + ua) * H_SZ + k0);
    float4 a2h = *(const float4*)(whh + (size_t)(512 + ua) * H_SZ + k0 + 4);
    float4 c0l = *(const float4*)(whh + (size_t)(ub)       * H_SZ + k0);
    float4 c0h = *(const float4*)(whh + (size_t)(ub)       * H_SZ + k0 + 4);
    float4 c1l = *(const float4*)(whh + (size_t)(256 + ub) * H_SZ + k0);
    float4 c1h = *(const float4*)(whh + (size_t)(256 + ub) * H_SZ + k0 + 4);
    float4 c2l = *(const float4*)(whh + (size_t)(512 + ub) * H_SZ + k0);
    float4 c2h = *(const float4*)(whh + (size_t)(512 + ub) * H_SZ + k0 + 4);
    PIN4(a0l) PIN4(a0h) PIN4(a1l) PIN4(a1h) PIN4(a2l) PIN4(a2h)
    PIN4(c0l) PIN4(c0h) PIN4(c1l) PIN4(c1h) PIN4(c2l) PIN4(c2h)

    const float bsrA = bih[ua]       + bhh[ua];
    const float bszA = bih[256 + ua] + bhh[256 + ua];
    const float bsnA = bih[512 + ua] + bhh[512 + ua];
    const float bsrB = bih[ub]       + bhh[ub];
    const float bszB = bih[256 + ub] + bhh[256 + ub];
    const float bsnB = bih[512 + ub] + bhh[512 + ub];

    const float* gxp = (p < 8) ? gx + ((size_t)(8 * g + p) * tc) * G3 + ua : nullptr;

    // gather mapping: thread polls 4 slots (n_t, units c_t..c_t+3)
    const int n_t = t >> 6;
    const int c_t = 4 * (t & 63);
    const int kct = kpad(c_t);
    const int kp8 = kpad(k0);
    const int kua = kpad(ua);
    // out-store mapping (t<64)
    const int n_o = t >> 3, f_o = t & 7;

    const bool kb0 = (p & 1) != 0, kb1 = (p & 2) != 0, kb2 = (p & 4) != 0;

    // preload gx(u=0)
    float gxrA = 0.f, gxzA = 0.f, gxnA = 0.f, gxrB = 0.f, gxzB = 0.f, gxnB = 0.f;
    if (p < 8) {
        gxrA = gxp[0];   gxzA = gxp[256]; gxnA = gxp[512];
        gxrB = gxp[1];   gxzB = gxp[257]; gxnB = gxp[513];
    }

#pragma unroll 1
    for (int u = 0; u < tc; ++u) {
        const int tg  = gbase + u;
        const int par = tg & 1;

        // ---- coalesced out-store for step u-1 (hst stable since last barrier) ----
        if (u > 0 && t < 64) {
            float4 o;
            o.x = hst[n_o][4 * f_o];     o.y = hst[n_o][4 * f_o + 1];
            o.z = hst[n_o][4 * f_o + 2]; o.w = hst[n_o][4 * f_o + 3];
            *(float4*)(out + ((size_t)(8 * g + n_o) * T_SZ + (tg - 1)) * H_SZ + u0 + 4 * f_o) = o;
        }

        // ---- gather h(tg): poll 4 packed slots (data arrives WITH version) ----
        {
            unsigned long long* sb = xch + xsl(g, par, n_t, c_t);
            const unsigned want = (unsigned)tg;
            unsigned long long v0, v1, v2, v3;
            int sp = 0;
            for (;;) {
                v0 = __hip_atomic_load(sb + 0, __ATOMIC_RELAXED, __HIP_MEMORY_SCOPE_AGENT);
                v1 = __hip_atomic_load(sb + 1, __ATOMIC_RELAXED, __HIP_MEMORY_SCOPE_AGENT);
                v2 = __hip_atomic_load(sb + 2, __ATOMIC_RELAXED, __HIP_MEMORY_SCOPE_AGENT);
                v3 = __hip_atomic_load(sb + 3, __ATOMIC_RELAXED, __HIP_MEMORY_SCOPE_AGENT);
                bool ok = ((unsigned)(v0 >> 32) == want) & ((unsigned)(v1 >> 32) == want) &
                          ((unsigned)(v2 >> 32) == want) & ((unsigned)(v3 >> 32) == want);
                if (ok || ++sp >= SPIN_MAX) break;
                __builtin_amdgcn_s_sleep(2);
            }
            float4 hv;
            hv.x = __uint_as_float((unsigned)v0);
            hv.y = __uint_as_float((unsigned)v1);
            hv.z = __uint_as_float((unsigned)v2);
            hv.w = __uint_as_float((unsigned)v3);
            *(float4*)&hl[n_t][kct] = hv;
        }
        __syncthreads();

        // ---- prefetch gx(u+1) ----
        float pgrA = 0.f, pgzA = 0.f, pgnA = 0.f, pgrB = 0.f, pgzB = 0.f, pgnB = 0.f;
        if (p < 8 && u + 1 < tc) {
            size_t go = (size_t)(u + 1) * G3;
            pgrA = gxp[go];     pgzA = gxp[go + 256]; pgnA = gxp[go + 512];
            pgrB = gxp[go + 1]; pgzB = gxp[go + 257]; pgnB = gxp[go + 513];
        }

        // ---- matvec: 16 b128 h-reads, 384 FMA into 48 accs ----
        float aA0[8], aA1[8], aA2[8], aB0[8], aB1[8], aB2[8];
#pragma unroll
        for (int n = 0; n < 8; ++n) {
            float4 h0v = *(const float4*)&hl[n][kp8];
            float4 h1v = *(const float4*)&hl[n][kp8 + 4];
            aA0[n] = d8(0.f, a0l, a0h, h0v, h1v);
            aA1[n] = d8(0.f, a1l, a1h, h0v, h1v);
            aA2[n] = d8(0.f, a2l, a2h, h0v, h1v);
            aB0[n] = d8(0.f, c0l, c0h, h0v, h1v);
            aB1[n] = d8(0.f, c1l, c1h, h0v, h1v);
            aB2[n] = d8(0.f, c2l, c2h, h0v, h1v);
        }

        // ---- keep/send butterfly over 32 lanes ----
        // stage xor1 (n bit0): 48 -> 24
        float r1A0[4], r1A1[4], r1A2[4], r1B0[4], r1B1[4], r1B2[4];
#pragma unroll
        for (int i = 0; i < 4; ++i) {
            float K, S;
            K = kb0 ? aA0[2*i+1] : aA0[2*i]; S = kb0 ? aA0[2*i] : aA0[2*i+1];
            r1A0[i] = K + dppx<0xB1>(S);
            K = kb0 ? aA1[2*i+1] : aA1[2*i]; S = kb0 ? aA1[2*i] : aA1[2*i+1];
            r1A1[i] = K + dppx<0xB1>(S);
            K = kb0 ? aA2[2*i+1] : aA2[2*i]; S = kb0 ? aA2[2*i] : aA2[2*i+1];
            r1A2[i] = K + dppx<0xB1>(S);
            K = kb0 ? aB0[2*i+1] : aB0[2*i]; S = kb0 ? aB0[2*i] : aB0[2*i+1];
            r1B0[i] = K + dppx<0xB1>(S);
            K = kb0 ? aB1[2*i+1] : aB1[2*i]; S = kb0 ? aB1[2*i] : aB1[2*i+1];
            r1B1[i] = K + dppx<0xB1>(S);
            K = kb0 ? aB2[2*i+1] : aB2[2*i]; S = kb0 ? aB2[2*i] : aB2[2*i+1];
            r1B2[i] = K + dppx<0xB1>(S);
        }
        // stage xor2 (n bit1): 24 -> 12
        float r2A0[2], r2A1[2], r2A2[2], r2B0[2], r2B1[2], r2B2[2];
#pragma unroll
        for (int i = 0; i < 2; ++i) {
            float K, S;
            K = kb1 ? r1A0[2*i+1] : r1A0[2*i]; S = kb1 ? r1A0[2*i] : r1A0[2*i+1];
            r2A0[i] = K + dppx<0x4E>(S);
            K = kb1 ? r1A1[2*i+1] : r1A1[2*i]; S = kb1 ? r1A1[2*i] : r1A1[2*i+1];
            r2A1[i] = K + dppx<0x4E>(S);
            K = kb1 ? r1A2[2*i+1] : r1A2[2*i]; S = kb1 ? r1A2[2*i] : r1A2[2*i+1];
            r2A2[i] = K + dppx<0x4E>(S);
            K = kb1 ? r1B0[2*i+1] : r1B0[2*i]; S = kb1 ? r1B0[2*i] : r1B0[2*i+1];
            r2B0[i] = K + dppx<0x4E>(S);
            K = kb1 ? r1B1[2*i+1] : r1B1[2*i]; S = kb1 ? r1B1[2*i] : r1B1[2*i+1];
            r2B1[i] = K + dppx<0x4E>(S);
            K = kb1 ? r1B2[2*i+1] : r1B2[2*i]; S = kb1 ? r1B2[2*i] : r1B2[2*i+1];
            r2B2[i] = K + dppx<0x4E>(S);
        }
        // stage xor4 (n bit2, ds_swizzle): 12 -> 6
        float sA0, sA1, sA2, sB0, sB1, sB2;
        {
            float K, S;
            K = kb2 ? r2A0[1] : r2A0[0]; S = kb2 ? r2A0[0] : r2A0[1];
            sA0 = K + swzx<0x101F>(S);
            K = kb2 ? r2A1[1] : r2A1[0]; S = kb2 ? r2A1[0] : r2A1[1];
            sA1 = K + swzx<0x101F>(S);
            K = kb2 ? r2A2[1] : r2A2[0]; S = kb2 ? r2A2[0] : r2A2[1];
            sA2 = K + swzx<0x101F>(S);
            K = kb2 ? r2B0[1] : r2B0[0]; S = kb2 ? r2B0[0] : r2B0[1];
            sB0 = K + swzx<0x101F>(S);
            K = kb2 ? r2B1[1] : r2B1[0]; S = kb2 ? r2B1[0] : r2B1[1];
            sB1 = K + swzx<0x101F>(S);
            K = kb2 ? r2B2[1] : r2B2[0]; S = kb2 ? r2B2[0] : r2B2[1];
            sB2 = K + swzx<0x101F>(S);
        }
        // plain xor8 (row_ror:8) then xor16 (ds_swizzle)
        sA0 += dppx<0x128>(sA0); sA1 += dppx<0x128>(sA1); sA2 += dppx<0x128>(sA2);
        sB0 += dppx<0x128>(sB0); sB1 += dppx<0x128>(sB1); sB2 += dppx<0x128>(sB2);
        sA0 += swzx<0x401F>(sA0); sA1 += swzx<0x401F>(sA1); sA2 += swzx<0x401F>(sA2);
        sB0 += swzx<0x401F>(sB0); sB1 += swzx<0x401F>(sB1); sB2 += swzx<0x401F>(sB2);

        // ---- gates + publish (p<8, batch n=p, units ua/ub) ----
        if (p < 8) {
            float holdA = hl[p][kua];
            float holdB = hl[p][kua + 1];   // kpad(ub)=kpad(ua)+1 (ua even)
            float arA = sA0 + gxrA + bsrA;
            float azA = sA1 + gxzA + bszA;
            float anA = sA2 + gxnA + bsnA;
            float arB = sB0 + gxrB + bsrB;
            float azB = sB1 + gxzB + bszB;
            float anB = sB2 + gxnB + bsnB;
            float rA = 1.f / (1.f + expf(-arA));
            float zA = 1.f / (1.f + expf(-azA));
            float nA = tanhf(rA * anA);
            float rB = 1.f / (1.f + expf(-arB));
            float zB = 1.f / (1.f + expf(-azB));
            float nB = tanhf(rB * anB);
            float hnA = (1.f - zA) * holdA + zA * nA;
            float hnB = (1.f - zB) * holdB + zB * nB;

            hst[p][2 * j2]     = hnA;
            hst[p][2 * j2 + 1] = hnB;
            const unsigned long long ver = (unsigned long long)(unsigned)(tg + 1) << 32;
            const int par1 = (tg + 1) & 1;
            __hip_atomic_store(xch + xsl(g, par1, p, ua),
                               ver | (unsigned long long)__float_as_uint(hnA),
                               __ATOMIC_RELAXED, __HIP_MEMORY_SCOPE_AGENT);
            __hip_atomic_store(xch + xsl(g, par1, p, ub),
                               ver | (unsigned long long)__float_as_uint(hnB),
                               __ATOMIC_RELAXED, __HIP_MEMORY_SCOPE_AGENT);
        }
        gxrA = pgrA; gxzA = pgzA; gxnA = pgnA;
        gxrB = pgrB; gxzB = pgzB; gxnB = pgnB;
        __syncthreads();   // hl reads done; hst visible; publishes drained
    }

    // ---- flush last step's out row (+ h_last) ----
    if (t < 64) {
        float4 o;
        o.x = hst[n_o][4 * f_o];     o.y = hst[n_o][4 * f_o + 1];
        o.z = hst[n_o][4 * f_o + 2]; o.w = hst[n_o][4 * f_o + 3];
        *(float4*)(out + ((size_t)(8 * g + n_o) * T_SZ + (gbase + tc - 1)) * H_SZ + u0 + 4 * f_o) = o;
        if (isLast)
            *(float4*)(out + (size_t)B_SZ * T_SZ * H_SZ
                           + (size_t)(8 * g + n_o) * H_SZ + u0 + 4 * f_o) = o;
    }
}

// ---------------- host ----------------
extern "C" void kernel_launch(void* const* d_in, const int* in_sizes, int n_in,
                              void* d_out, int out_size, void* d_ws, size_t ws_size,
                              hipStream_t stream) {
    const float* x   = (const float*)d_in[0];
    const float* h0  = (const float*)d_in[1];
    const float* wih = (const float*)d_in[2];
    const float* whh = (const float*)d_in[3];
    const float* bih = (const float*)d_in[4];
    const float* bhh = (const float*)d_in[5];
    float* out = (float*)d_out;

    char* ws = (char*)d_ws;
    const size_t xchB = (size_t)NGRP * 2 * 8 * 256 * 8;   // 1 MiB
    unsigned long long* xch = (unsigned long long*)ws;
    float* gxb = (float*)(ws + xchB);

    int tcShift = 10;
    while (tcShift > 0 &&
           xchB + (786432ull << tcShift) > ws_size) --tcShift;
    const int TC  = 1 << tcShift;
    const int nCh = T_SZ / TC;

    prep_kernel<<<dim3(256), dim3(256), 0, stream>>>(h0, xch);
    for (int c = 0; c < nCh; ++c) {
        gemm_x_kernel<<<dim3(B_SZ * TC / 64, 6), dim3(256), 0, stream>>>(
            x, wih, gxb, c, tcShift);
        gru_kernel<<<dim3(B_SZ), dim3(512), 0, stream>>>(
            gxb, whh, bih, bhh, xch, out, c * TC, TC, (c == nCh - 1) ? 1 : 0);
    }
}